// Round 1
// 487.633 us; speedup vs baseline: 1.0212x; 1.0212x over previous
//
#include <hip/hip_runtime.h>
#include <hip/hip_bf16.h>
#include <stdint.h>

#define NB 32
#define NS 4096
#define ND 512

typedef __attribute__((ext_vector_type(8))) short short8;
typedef __attribute__((ext_vector_type(4))) float floatx4;
typedef __attribute__((ext_vector_type(4))) unsigned int uint4v;

__device__ __forceinline__ short f2bf(float f) {
    unsigned int u = __builtin_bit_cast(unsigned int, f);
    return (short)((u + 0x8000u) >> 16);
}

// one instr, packs 2 f32 -> 2 bf16 (RNE)
__device__ __forceinline__ unsigned int cvt_pk_bf16(float lo, float hi) {
    unsigned int r;
    asm("v_cvt_pk_bf16_f32 %0, %1, %2" : "=v"(r) : "v"(lo), "v"(hi));
    return r;
}

__device__ __forceinline__ float fast_tanh(float x) {
    float e = __expf(2.0f * x);
    return 1.0f - 2.0f * __builtin_amdgcn_rcpf(e + 1.0f);
}

// K1a: qb[b][e] = sum_k query[b][k] * W1[k][e] + b1[e] + b2[e]
__global__ void __launch_bounds__(256) qproj_kernel(
    const float* __restrict__ query, const float* __restrict__ W1,
    const float* __restrict__ b1, const float* __restrict__ b2,
    float* __restrict__ qb) {
    const int b  = blockIdx.x;
    const int es = blockIdx.y;
    const int t  = threadIdx.x;
    const int col = t & 63, kc = t >> 6;
    __shared__ float q[ND];
    __shared__ float red[256];
    q[t] = query[b * ND + t];
    q[t + 256] = query[b * ND + t + 256];
    __syncthreads();
    float acc = 0.f;
    const float* wp = W1 + (size_t)(kc * 128) * ND + es * 64 + col;
    const float* qp = q + kc * 128;
#pragma unroll 8
    for (int k = 0; k < 128; k++)
        acc += qp[k] * wp[(size_t)k * ND];
    red[t] = acc;
    __syncthreads();
    if (t < 64) {
        float s = red[t] + red[t + 64] + red[t + 128] + red[t + 192];
        int e = es * 64 + t;
        qb[b * ND + e] = s + b1[e] + b2[e];
    }
}

// K1b: shuffle W2 (fp32 [k][e]) into bf16 tiled layout for global_load_lds:
// chunk g = (nt: g>>14, ks: (g>>10)&15, kq: (g>>8)&3, n: g&255);
// holds bf16(W2[ks*32+kq*8+j][nt*256+n]) for j=0..7 at W2Tt + g*8.
__global__ void __launch_bounds__(256) w2t_kernel(
    const float* __restrict__ W2, unsigned short* __restrict__ W2Tt) {
    int g = blockIdx.x * 256 + threadIdx.x;   // 32768 chunks
    int nt = g >> 14;
    int ks = (g >> 10) & 15;
    int kq = (g >> 8) & 3;
    int n  = g & 255;
    int e  = nt * 256 + n;
    int k0 = ks * 32 + kq * 8;
    short8 v;
#pragma unroll
    for (int j = 0; j < 8; j++)
        v[j] = f2bf(W2[(size_t)(k0 + j) * ND + e]);
    *(short8*)&W2Tt[(size_t)g * 8] = v;
}

// K2: pscores[nt][b][s] = sum_{e in 256-wide ntile} tanh((values[b] @ W2)[s][e] + qb[b][e]) * V[e]
// Tile 64 s-rows x 256 n-cols, K=512 in 16 steps of 32. 4 waves, each 64x64 (acc 4x4).
// A: reg-staged fp32 -> cvt_pk bf16 ONCE -> ds_write_b128 (chunk-XOR swizzle, 2-way banks),
//    prefetched 2 K-steps deep in VGPRs so HBM latency never hits the pre-barrier drain.
// B: bf16 via global_load_lds from pre-shuffled W2Tt (L2-resident), prefetch depth 1.
// Epilogue: tanh(P+qb)*V, shfl + LDS cross-wave reduce, direct store (no atomics/memset).
__global__ void __launch_bounds__(256, 3) scores_kernel(
    const float* __restrict__ values, const unsigned short* __restrict__ W2Tt,
    const float* __restrict__ qb, const float* __restrict__ V,
    float* __restrict__ pscores) {
    const int nt = blockIdx.x;   // 0..1
    const int st = blockIdx.y;   // 0..63
    const int b  = blockIdx.z;   // 0..31
    const int n0 = nt * 256, s0 = st * 64;

    __shared__ __align__(16) unsigned short sA[2][2048];   // 2 x 4 KB bf16 (64 rows x 32 k, swz)
    __shared__ __align__(16) unsigned short sB[2][8192];   // 2 x 16 KB bf16 (256 n x 32 k)
    __shared__ float sQb[256];
    __shared__ float sV[256];
    __shared__ float sRed[4][64];

    const int tid  = threadIdx.x;
    const int lane = tid & 63;
    const int wave = tid >> 6;          // 0..3 -> n-col offset wave*64
    const int mr = lane & 15;
    const int q  = lane >> 4;

    sQb[tid] = qb[b * ND + n0 + tid];
    sV[tid]  = V[n0 + tid];

    floatx4 acc[4][4] = {};

    // A staging geometry: thread -> (row = tid>>2, k-chunk c = tid&3), 8 fp32 each.
    // chunk stored at position c ^ ((row>>1)&3): spreads 16 rows over 8 bank-groups (2-way = free)
    const int arow = tid >> 2;
    const int ac   = tid & 3;
    const int ardo = arow * 32 + ((ac ^ ((tid >> 3) & 3)) * 8);  // short offset, 16B aligned
    const float* ag = values + ((size_t)b * NS + s0 + arow) * ND + ac * 8;

    // frag-read chunk offset: row=i*16+mr -> (row>>1)&3 == (mr>>1)&3 (i*8 == 0 mod 4)
    const int afo = (q ^ ((mr >> 1) & 3)) * 8;

    const unsigned short* bbase = W2Tt + (size_t)(nt * 16) * 8192;

    // ---- prologue: A(0)->LDS, A(1)->regs, B(0)->LDS ----
    float4 p0 = *(const float4*)(ag);
    float4 p1 = *(const float4*)(ag + 4);
    float4 arA0 = *(const float4*)(ag + 32);
    float4 arA1 = *(const float4*)(ag + 36);
#pragma unroll
    for (int r = 0; r < 4; r++) {
        int c = tid + 256 * r;
        __builtin_amdgcn_global_load_lds(
            (const __attribute__((address_space(1))) unsigned int*)(bbase + c * 8),
            (__attribute__((address_space(3))) unsigned int*)&sB[0][c * 8],
            16, 0, 0);
    }
    {
        uint4v w;
        w.x = cvt_pk_bf16(p0.x, p0.y); w.y = cvt_pk_bf16(p0.z, p0.w);
        w.z = cvt_pk_bf16(p1.x, p1.y); w.w = cvt_pk_bf16(p1.z, p1.w);
        *(uint4v*)&sA[0][ardo] = w;
    }
    __syncthreads();

#pragma unroll
    for (int ks = 0; ks < 16; ks++) {
        const int cur = ks & 1, nxt = cur ^ 1;

        // ---- frag reads of [cur] (4+4 ds_read_b128, all bf16, 2-way banks) ----
        short8 af[4], bfr[4];
#pragma unroll
        for (int i = 0; i < 4; i++)
            af[i] = *(const short8*)&sA[cur][(i * 16 + mr) * 32 + afo];
#pragma unroll
        for (int j = 0; j < 4; j++)
            bfr[j] = *(const short8*)&sB[cur][(q * 256 + wave * 64 + j * 16 + mr) * 8];

        // ---- B(ks+1) -> sB[nxt] (L2-hit, drained at barrier, covered by MFMA) ----
        if (ks < 15) {
            const unsigned short* bsrc = bbase + (size_t)(ks + 1) * 8192;
#pragma unroll
            for (int r = 0; r < 4; r++) {
                int c = tid + 256 * r;
                __builtin_amdgcn_global_load_lds(
                    (const __attribute__((address_space(1))) unsigned int*)(bsrc + c * 8),
                    (__attribute__((address_space(3))) unsigned int*)&sB[nxt][c * 8],
                    16, 0, 0);
            }
        }
        // ---- A(ks+2) -> regs (full K-step of HBM latency cover) ----
        float4 n0v = {}, n1v = {};
        if (ks < 14) {
            n0v = *(const float4*)(ag + (ks + 2) * 32);
            n1v = *(const float4*)(ag + (ks + 2) * 32 + 4);
        }

#pragma unroll
        for (int i = 0; i < 4; i++)
#pragma unroll
            for (int j = 0; j < 4; j++)
                acc[i][j] = __builtin_amdgcn_mfma_f32_16x16x32_bf16(af[i], bfr[j], acc[i][j], 0, 0, 0);

        // ---- A(ks+1) regs -> cvt_pk -> sA[nxt] (loads landed one step ago) ----
        if (ks < 15) {
            uint4v w;
            w.x = cvt_pk_bf16(arA0.x, arA0.y); w.y = cvt_pk_bf16(arA0.z, arA0.w);
            w.z = cvt_pk_bf16(arA1.x, arA1.y); w.w = cvt_pk_bf16(arA1.z, arA1.w);
            *(uint4v*)&sA[nxt][ardo] = w;
        }
        arA0 = n0v; arA1 = n1v;

        __syncthreads();
    }

    // ---- epilogue: tanh(P + qb) * V, reduce over 64 wave-cols then cross-wave ----
    float vcoef[4], qadd[4];
#pragma unroll
    for (int j = 0; j < 4; j++) {
        int col = wave * 64 + j * 16 + mr;
        vcoef[j] = sV[col];
        qadd[j]  = sQb[col];
    }

#pragma unroll
    for (int i = 0; i < 4; i++) {
#pragma unroll
        for (int r = 0; r < 4; r++) {
            float p = 0.f;
#pragma unroll
            for (int j = 0; j < 4; j++)
                p += fast_tanh(acc[i][j][r] + qadd[j]) * vcoef[j];
            p += __shfl_xor(p, 1);
            p += __shfl_xor(p, 2);
            p += __shfl_xor(p, 4);
            p += __shfl_xor(p, 8);
            if (mr == 0) sRed[wave][i * 16 + q * 4 + r] = p;
        }
    }
    __syncthreads();
    if (tid < 64) {
        float s = sRed[0][tid] + sRed[1][tid] + sRed[2][tid] + sRed[3][tid];
        pscores[((size_t)nt * NB + b) * NS + s0 + tid] = s;
    }
}

// K3: softmax over S per batch; sums the two nt partial planes on the fly
__global__ void __launch_bounds__(256) softmax_kernel(
    const float* __restrict__ pscores, float* __restrict__ attn) {
    int b = blockIdx.x;
    int t = threadIdx.x;
    __shared__ float red[4];
    __shared__ float bcast[2];
    const float* sc0 = pscores + (size_t)b * NS;
    const float* sc1 = pscores + (size_t)(NB + b) * NS;
    float v[16];
    float m = -1e30f;
#pragma unroll
    for (int i = 0; i < 16; i++) {
        v[i] = sc0[t + i * 256] + sc1[t + i * 256];
        m = fmaxf(m, v[i]);
    }
    for (int o = 32; o; o >>= 1) m = fmaxf(m, __shfl_xor(m, o));
    if ((t & 63) == 0) red[t >> 6] = m;
    __syncthreads();
    if (t == 0) bcast[0] = fmaxf(fmaxf(red[0], red[1]), fmaxf(red[2], red[3]));
    __syncthreads();
    m = bcast[0];
    float sum = 0.f;
#pragma unroll
    for (int i = 0; i < 16; i++) { v[i] = __expf(v[i] - m); sum += v[i]; }
    for (int o = 32; o; o >>= 1) sum += __shfl_xor(sum, o);
    if ((t & 63) == 0) red[t >> 6] = sum;
    __syncthreads();
    if (t == 0) bcast[1] = red[0] + red[1] + red[2] + red[3];
    __syncthreads();
    float inv = 1.0f / bcast[1];
    float* ao = attn + (size_t)b * NS;
#pragma unroll
    for (int i = 0; i < 16; i++) ao[t + i * 256] = v[i] * inv;
}

// K4a: pctx[sc][b][d] = sum_{s in 256-chunk} attn[b][s] * values[b][s][d]
// 512 blocks (2/CU) for latency tolerance on the strided value reads.
__global__ void __launch_bounds__(256) context_partial_kernel(
    const float* __restrict__ values, const float* __restrict__ attn,
    float* __restrict__ pctx) {
    int sc = blockIdx.x;  // 0..15 (256 s each)
    int b  = blockIdx.y;  // 0..31
    int t  = threadIdx.x;
    __shared__ float sAttn[256];
    sAttn[t] = attn[(size_t)b * NS + sc * 256 + t];
    __syncthreads();
    int d = t * 2;
    const float2* vp = (const float2*)(values + ((size_t)b * NS + sc * 256) * ND + d);
    float ax = 0.f, ay = 0.f;
#pragma unroll 8
    for (int s = 0; s < 256; s++) {
        float a = sAttn[s];
        float2 v = vp[(size_t)s * 256];
        ax += a * v.x; ay += a * v.y;
    }
    pctx[((size_t)sc * 32 + b) * ND + d]     = ax;
    pctx[((size_t)sc * 32 + b) * ND + d + 1] = ay;
}

// K4b: ctx[b][d] = sum_sc pctx[sc][b][d]
__global__ void __launch_bounds__(256) context_reduce_kernel(
    const float* __restrict__ pctx, float* __restrict__ ctx) {
    int i = blockIdx.x * 256 + threadIdx.x;  // 16384
    float s = 0.f;
#pragma unroll
    for (int p = 0; p < 16; p++) s += pctx[(size_t)p * (32 * ND) + i];
    ctx[i] = s;
}

extern "C" void kernel_launch(void* const* d_in, const int* in_sizes, int n_in,
                              void* d_out, int out_size, void* d_ws, size_t ws_size,
                              hipStream_t stream) {
    const float* query  = (const float*)d_in[0];
    const float* values = (const float*)d_in[1];
    const float* W1     = (const float*)d_in[2];
    const float* b1     = (const float*)d_in[3];
    const float* W2     = (const float*)d_in[4];
    const float* b2     = (const float*)d_in[5];
    const float* V      = (const float*)d_in[6];
    // d_in[7] = bv: uniform shift over softmax axis -> no effect on outputs. Dropped.

    float* ctx_out  = (float*)d_out;               // [32,512]
    float* attn_out = (float*)d_out + NB * ND;     // [32,4096]

    char* ws = (char*)d_ws;
    float*          qb      = (float*)ws;                              // 64 KB
    unsigned short* W2Tt    = (unsigned short*)(ws + (64 << 10));      // 512 KB
    float*          pscores = (float*)(ws + (576 << 10));              // 1 MB: [2][32][4096]
    float*          pctx    = pscores;   // aliased: softmax is done before K4a writes it

    qproj_kernel<<<dim3(NB, 8), 256, 0, stream>>>(query, W1, b1, b2, qb);
    w2t_kernel<<<128, 256, 0, stream>>>(W2, W2Tt);
    scores_kernel<<<dim3(2, 64, 32), 256, 0, stream>>>(values, W2Tt, qb, V, pscores);
    softmax_kernel<<<NB, 256, 0, stream>>>(pscores, attn_out);
    context_partial_kernel<<<dim3(16, 32), 256, 0, stream>>>(values, attn_out, pctx);
    context_reduce_kernel<<<64, 256, 0, stream>>>(pctx, ctx_out);
}

// Round 2
// 465.684 us; speedup vs baseline: 1.0693x; 1.0471x over previous
//
#include <hip/hip_runtime.h>
#include <hip/hip_bf16.h>
#include <stdint.h>

#define NB 32
#define NS 4096
#define ND 512

typedef __attribute__((ext_vector_type(8))) short short8;
typedef __attribute__((ext_vector_type(4))) float floatx4;
typedef __attribute__((ext_vector_type(4))) unsigned int uint4v;

__device__ __forceinline__ short f2bf(float f) {
    unsigned int u = __builtin_bit_cast(unsigned int, f);
    return (short)((u + 0x8000u) >> 16);
}

// one instr, packs 2 f32 -> 2 bf16 (RNE)
__device__ __forceinline__ unsigned int cvt_pk_bf16(float lo, float hi) {
    unsigned int r;
    asm("v_cvt_pk_bf16_f32 %0, %1, %2" : "=v"(r) : "v"(lo), "v"(hi));
    return r;
}

__device__ __forceinline__ float fast_tanh(float x) {
    float e = __expf(2.0f * x);
    return 1.0f - 2.0f * __builtin_amdgcn_rcpf(e + 1.0f);
}

// K1a: qb[b][e] = sum_k query[b][k] * W1[k][e] + b1[e] + b2[e]
__global__ void __launch_bounds__(256) qproj_kernel(
    const float* __restrict__ query, const float* __restrict__ W1,
    const float* __restrict__ b1, const float* __restrict__ b2,
    float* __restrict__ qb) {
    const int b  = blockIdx.x;
    const int es = blockIdx.y;
    const int t  = threadIdx.x;
    const int col = t & 63, kc = t >> 6;
    __shared__ float q[ND];
    __shared__ float red[256];
    q[t] = query[b * ND + t];
    q[t + 256] = query[b * ND + t + 256];
    __syncthreads();
    float acc = 0.f;
    const float* wp = W1 + (size_t)(kc * 128) * ND + es * 64 + col;
    const float* qp = q + kc * 128;
#pragma unroll 8
    for (int k = 0; k < 128; k++)
        acc += qp[k] * wp[(size_t)k * ND];
    red[t] = acc;
    __syncthreads();
    if (t < 64) {
        float s = red[t] + red[t + 64] + red[t + 128] + red[t + 192];
        int e = es * 64 + t;
        qb[b * ND + e] = s + b1[e] + b2[e];
    }
}

// K1b: shuffle W2 (fp32 [k][e]) into bf16 tiled layout so each lane's MFMA
// B-fragment is one contiguous 16B chunk:
// chunk g = (nt: g>>14, ks: (g>>10)&15, kq: (g>>8)&3, n: g&255);
// holds bf16(W2[ks*32+kq*8+j][nt*256+n]) for j=0..7 at W2Tt + g*8.
__global__ void __launch_bounds__(256) w2t_kernel(
    const float* __restrict__ W2, unsigned short* __restrict__ W2Tt) {
    int g = blockIdx.x * 256 + threadIdx.x;   // 32768 chunks
    int nt = g >> 14;
    int ks = (g >> 10) & 15;
    int kq = (g >> 8) & 3;
    int n  = g & 255;
    int e  = nt * 256 + n;
    int k0 = ks * 32 + kq * 8;
    short8 v;
#pragma unroll
    for (int j = 0; j < 8; j++)
        v[j] = f2bf(W2[(size_t)(k0 + j) * ND + e]);
    *(short8*)&W2Tt[(size_t)g * 8] = v;
}

// K2: pscores[nt][b][s] = sum_{e in 256-wide ntile} tanh((values[b] @ W2)[s][e] + qb[b][e]) * V[e]
// Tile 64 s-rows x 256 n-cols, K=512 in 16 steps of 32. 4 waves, each 64x64 (acc 4x4).
// B: direct per-lane global_load_dwordx4 from W2Tt (L2-resident), 1-step register prefetch.
//    Never in LDS -> no gload_lds, no B ds_reads, no vmcnt at the barrier.
// A: reg-staged fp32 (3-slot queue, ~2 steps HBM cover) -> cvt_pk bf16 -> ds_write b128
//    into XOR-swizzled double-buffered sA.
// Sync: RAW s_barrier with s_waitcnt lgkmcnt(0) only (T3/T4 idiom). All global loads
// target registers, so the compiler's counted vmcnt register-dep waits carry them
// across barriers -- prefetch survives, no vmcnt(0) drain ever.
__global__ void __launch_bounds__(256, 3) scores_kernel(
    const float* __restrict__ values, const unsigned short* __restrict__ W2Tt,
    const float* __restrict__ qb, const float* __restrict__ V,
    float* __restrict__ pscores) {
    const int nt = blockIdx.x;   // 0..1
    const int st = blockIdx.y;   // 0..63
    const int b  = blockIdx.z;   // 0..31
    const int n0 = nt * 256, s0 = st * 64;

    __shared__ __align__(16) unsigned short sA[2][2048];   // 2 x 4 KB bf16 (64 rows x 32 k, swz)
    __shared__ float sQb[256];
    __shared__ float sV[256];
    __shared__ float sRed[4][64];

    const int tid  = threadIdx.x;
    const int lane = tid & 63;
    const int wave = tid >> 6;          // 0..3 -> n-col offset wave*64
    const int mr = lane & 15;
    const int q  = lane >> 4;

    sQb[tid] = qb[b * ND + n0 + tid];
    sV[tid]  = V[n0 + tid];

    floatx4 acc[4][4] = {};

    // A staging geometry: thread -> (row = tid>>2, k-chunk c = tid&3), 8 fp32 each.
    // chunk stored at position c ^ ((row>>1)&3): conflict-free write, 2-way read aliasing
    const int arow = tid >> 2;
    const int ac   = tid & 3;
    const int ardo = arow * 32 + ((ac ^ ((tid >> 3) & 3)) * 8);  // short offset, 16B aligned
    const float* ag = values + ((size_t)b * NS + s0 + arow) * ND + ac * 8;

    // frag-read chunk offset: row=i*16+mr -> (row>>1)&3 == (mr>>1)&3
    const int afo = (q ^ ((mr >> 1) & 3)) * 8;

    // per-lane B pointer: fragment (wave, q, j, mr) chunk; j adds 256B, ks adds 16KB
    const unsigned short* bp = W2Tt + (size_t)nt * 16 * 8192 + (q * 256 + wave * 64 + mr) * 8;

    // ---- prologue: A chunk0 -> sA[0]; A chunks 1,2 -> reg queue; B step0 -> regs ----
    float4 p0 = *(const float4*)(ag);
    float4 p1 = *(const float4*)(ag + 4);
    float4 aq[3][2];                       // slot = chunk % 3 (all indices compile-time)
    aq[1][0] = *(const float4*)(ag + 32);  aq[1][1] = *(const float4*)(ag + 36);
    aq[2][0] = *(const float4*)(ag + 64);  aq[2][1] = *(const float4*)(ag + 68);
    short8 bq[2][4];
#pragma unroll
    for (int j = 0; j < 4; j++)
        bq[0][j] = *(const short8*)(bp + j * 128);
    {
        uint4v w;
        w.x = cvt_pk_bf16(p0.x, p0.y); w.y = cvt_pk_bf16(p0.z, p0.w);
        w.z = cvt_pk_bf16(p1.x, p1.y); w.w = cvt_pk_bf16(p1.z, p1.w);
        *(uint4v*)&sA[0][ardo] = w;
    }
    asm volatile("s_waitcnt lgkmcnt(0)" ::: "memory");
    __builtin_amdgcn_s_barrier();
    __builtin_amdgcn_sched_barrier(0);

#pragma unroll
    for (int ks = 0; ks < 16; ks++) {
        const int cur = ks & 1, nxt = cur ^ 1;

        // ---- A frag reads of [cur] (4 ds_read_b128) ----
        short8 af[4];
#pragma unroll
        for (int i = 0; i < 4; i++)
            af[i] = *(const short8*)&sA[cur][(i * 16 + mr) * 32 + afo];

        // ---- A chunk ks+1 (loaded at step ks-2) -> cvt -> sA[nxt] ----
        if (ks < 15) {
            const float4 a0 = aq[(ks + 1) % 3][0], a1 = aq[(ks + 1) % 3][1];
            uint4v w;
            w.x = cvt_pk_bf16(a0.x, a0.y); w.y = cvt_pk_bf16(a0.z, a0.w);
            w.z = cvt_pk_bf16(a1.x, a1.y); w.w = cvt_pk_bf16(a1.z, a1.w);
            *(uint4v*)&sA[nxt][ardo] = w;
        }

        // ---- issue B(ks+1) -> bq[nxt] (L2, lands under this step's MFMA) ----
        if (ks < 15) {
            const unsigned short* bsrc = bp + (size_t)(ks + 1) * 8192;
#pragma unroll
            for (int j = 0; j < 4; j++)
                bq[nxt][j] = *(const short8*)(bsrc + j * 128);
        }
        // ---- issue A chunk ks+3 -> freed slot (2-step HBM cover) ----
        if (ks < 13) {
            aq[ks % 3][0] = *(const float4*)(ag + (ks + 3) * 32);
            aq[ks % 3][1] = *(const float4*)(ag + (ks + 3) * 32 + 4);
        }

        __builtin_amdgcn_s_setprio(1);
#pragma unroll
        for (int i = 0; i < 4; i++)
#pragma unroll
            for (int j = 0; j < 4; j++)
                acc[i][j] = __builtin_amdgcn_mfma_f32_16x16x32_bf16(af[i], bq[cur][j], acc[i][j], 0, 0, 0);
        __builtin_amdgcn_s_setprio(0);

        // only LDS visibility is needed at the barrier; global prefetches stay in flight
        asm volatile("s_waitcnt lgkmcnt(0)" ::: "memory");
        __builtin_amdgcn_s_barrier();
        __builtin_amdgcn_sched_barrier(0);
    }

    // ---- epilogue: tanh(P + qb) * V, reduce over 64 wave-cols then cross-wave ----
    float vcoef[4], qadd[4];
#pragma unroll
    for (int j = 0; j < 4; j++) {
        int col = wave * 64 + j * 16 + mr;
        vcoef[j] = sV[col];
        qadd[j]  = sQb[col];
    }

#pragma unroll
    for (int i = 0; i < 4; i++) {
#pragma unroll
        for (int r = 0; r < 4; r++) {
            float p = 0.f;
#pragma unroll
            for (int j = 0; j < 4; j++)
                p += fast_tanh(acc[i][j][r] + qadd[j]) * vcoef[j];
            p += __shfl_xor(p, 1);
            p += __shfl_xor(p, 2);
            p += __shfl_xor(p, 4);
            p += __shfl_xor(p, 8);
            if (mr == 0) sRed[wave][i * 16 + q * 4 + r] = p;
        }
    }
    __syncthreads();
    if (tid < 64) {
        float s = sRed[0][tid] + sRed[1][tid] + sRed[2][tid] + sRed[3][tid];
        pscores[((size_t)nt * NB + b) * NS + s0 + tid] = s;
    }
}

// K3: softmax over S per batch; sums the two nt partial planes on the fly
__global__ void __launch_bounds__(256) softmax_kernel(
    const float* __restrict__ pscores, float* __restrict__ attn) {
    int b = blockIdx.x;
    int t = threadIdx.x;
    __shared__ float red[4];
    __shared__ float bcast[2];
    const float* sc0 = pscores + (size_t)b * NS;
    const float* sc1 = pscores + (size_t)(NB + b) * NS;
    float v[16];
    float m = -1e30f;
#pragma unroll
    for (int i = 0; i < 16; i++) {
        v[i] = sc0[t + i * 256] + sc1[t + i * 256];
        m = fmaxf(m, v[i]);
    }
    for (int o = 32; o; o >>= 1) m = fmaxf(m, __shfl_xor(m, o));
    if ((t & 63) == 0) red[t >> 6] = m;
    __syncthreads();
    if (t == 0) bcast[0] = fmaxf(fmaxf(red[0], red[1]), fmaxf(red[2], red[3]));
    __syncthreads();
    m = bcast[0];
    float sum = 0.f;
#pragma unroll
    for (int i = 0; i < 16; i++) { v[i] = __expf(v[i] - m); sum += v[i]; }
    for (int o = 32; o; o >>= 1) sum += __shfl_xor(sum, o);
    if ((t & 63) == 0) red[t >> 6] = sum;
    __syncthreads();
    if (t == 0) bcast[1] = red[0] + red[1] + red[2] + red[3];
    __syncthreads();
    float inv = 1.0f / bcast[1];
    float* ao = attn + (size_t)b * NS;
#pragma unroll
    for (int i = 0; i < 16; i++) ao[t + i * 256] = v[i] * inv;
}

// K4a: pctx[sc][b][d] = sum_{s in 256-chunk} attn[b][s] * values[b][s][d]
// float4 loads: 128 lanes cover a full 2KB row; two row-parity halves reduced via LDS.
__global__ void __launch_bounds__(256) context_partial_kernel(
    const float* __restrict__ values, const float* __restrict__ attn,
    float* __restrict__ pctx) {
    int sc = blockIdx.x;  // 0..15 (256 s each)
    int b  = blockIdx.y;  // 0..31
    int t  = threadIdx.x;
    __shared__ float sAttn[256];
    __shared__ float4 sRed4[256];
    sAttn[t] = attn[(size_t)b * NS + sc * 256 + t];
    __syncthreads();
    const int half = t >> 7;          // row parity
    const int d0 = (t & 127) * 4;
    const float* vp = values + ((size_t)b * NS + sc * 256 + half) * ND + d0;
    float4 acc = {0.f, 0.f, 0.f, 0.f};
#pragma unroll 8
    for (int s = 0; s < 128; s++) {
        float a = sAttn[s * 2 + half];
        float4 v = *(const float4*)(vp + (size_t)s * 2 * ND);
        acc.x += a * v.x; acc.y += a * v.y; acc.z += a * v.z; acc.w += a * v.w;
    }
    sRed4[t] = acc;
    __syncthreads();
    if (t < 128) {
        float4 r0 = sRed4[t], r1 = sRed4[t + 128];
        float4 o = {r0.x + r1.x, r0.y + r1.y, r0.z + r1.z, r0.w + r1.w};
        *(float4*)&pctx[((size_t)sc * 32 + b) * ND + d0] = o;
    }
}

// K4b: ctx[b][d] = sum_sc pctx[sc][b][d]
__global__ void __launch_bounds__(256) context_reduce_kernel(
    const float* __restrict__ pctx, float* __restrict__ ctx) {
    int i = blockIdx.x * 256 + threadIdx.x;  // 16384
    float s = 0.f;
#pragma unroll
    for (int p = 0; p < 16; p++) s += pctx[(size_t)p * (32 * ND) + i];
    ctx[i] = s;
}

extern "C" void kernel_launch(void* const* d_in, const int* in_sizes, int n_in,
                              void* d_out, int out_size, void* d_ws, size_t ws_size,
                              hipStream_t stream) {
    const float* query  = (const float*)d_in[0];
    const float* values = (const float*)d_in[1];
    const float* W1     = (const float*)d_in[2];
    const float* b1     = (const float*)d_in[3];
    const float* W2     = (const float*)d_in[4];
    const float* b2     = (const float*)d_in[5];
    const float* V      = (const float*)d_in[6];
    // d_in[7] = bv: uniform shift over softmax axis -> no effect on outputs. Dropped.

    float* ctx_out  = (float*)d_out;               // [32,512]
    float* attn_out = (float*)d_out + NB * ND;     // [32,4096]

    char* ws = (char*)d_ws;
    float*          qb      = (float*)ws;                              // 64 KB
    unsigned short* W2Tt    = (unsigned short*)(ws + (64 << 10));      // 512 KB
    float*          pscores = (float*)(ws + (576 << 10));              // 1 MB: [2][32][4096]
    float*          pctx    = pscores;   // aliased: softmax is done before K4a writes it

    qproj_kernel<<<dim3(NB, 8), 256, 0, stream>>>(query, W1, b1, b2, qb);
    w2t_kernel<<<128, 256, 0, stream>>>(W2, W2Tt);
    scores_kernel<<<dim3(2, 64, 32), 256, 0, stream>>>(values, W2Tt, qb, V, pscores);
    softmax_kernel<<<NB, 256, 0, stream>>>(pscores, attn_out);
    context_partial_kernel<<<dim3(16, 32), 256, 0, stream>>>(values, attn_out, pctx);
    context_reduce_kernel<<<64, 256, 0, stream>>>(pctx, ctx_out);
}